// Round 3
// baseline (616.812 us; speedup 1.0000x reference)
//
#include <hip/hip_runtime.h>

#define T_STEPS 512
#define HID 64

typedef short bf16x8 __attribute__((ext_vector_type(8)));
typedef float f32x4 __attribute__((ext_vector_type(4)));

__device__ __forceinline__ float sigm(float x) {
  return __builtin_amdgcn_rcpf(1.f + __expf(-x));
}
__device__ __forceinline__ float tanh_fast(float x) {
  return 1.f - 2.f * __builtin_amdgcn_rcpf(__expf(2.f * x) + 1.f);
}

// split fp32 -> bf16 hi (chop) + bf16 lo (chop of exact residual)
__device__ __forceinline__ void split1(float v, short* hi, short* lo) {
  unsigned u = __float_as_uint(v);
  float r = v - __uint_as_float(u & 0xffff0000u);   // exact in fp32
  *hi = (short)(u >> 16);
  *lo = (short)(__float_as_uint(r) >> 16);
}

__device__ __forceinline__ void split8(const float* __restrict__ p, bf16x8& hi, bf16x8& lo) {
  float v[8];
  *(float4*)&v[0] = *(const float4*)p;
  *(float4*)&v[4] = *(const float4*)(p + 4);
  #pragma unroll
  for (int i = 0; i < 8; ++i) {
    unsigned u = __float_as_uint(v[i]);
    float r = v[i] - __uint_as_float(u & 0xffff0000u);
    hi[i] = (short)(u >> 16);
    lo[i] = (short)(__float_as_uint(r) >> 16);
  }
}

#define MM(acc, A, B) acc = __builtin_amdgcn_mfma_f32_16x16x32_bf16((A), (B), (acc), 0, 0, 0)

// depth-3 chains per K-chunk: Wh*vh + Wh*vl + Wl*vh  (drop Wl*vl, as verified)
#define G3C0(acc, VH0, VL0, NM) do { \
    MM(acc, VH0, NM##h0); MM(acc, VL0, NM##h0); MM(acc, VH0, NM##l0); } while (0)
#define G3C1(acc, VH1, VL1, NM) do { \
    MM(acc, VH1, NM##h1); MM(acc, VL1, NM##h1); MM(acc, VH1, NM##l1); } while (0)

#define WFRAG(NM, Wp, goff) \
  bf16x8 NM##h0, NM##l0, NM##h1, NM##l1; \
  split8((Wp) + (goff) * (64 * HID) + wrowoff, NM##h0, NM##l0); \
  split8((Wp) + (goff) * (64 * HID) + wrowoff + 32, NM##h1, NM##l1)

// LDS A-matrices: logical [m(16)][k(64)] bf16, stored XOR-swizzled in 16B units:
// element idx (shorts) = m*64 + (((k>>3) ^ (m&7))<<3) + (k&7).
// Fragment read (chunk c, lane (nloc,quad)): base = nloc*64 + (((c*4+quad)^(nloc&7))<<3)
// -> conflict-free b128. Batches live at rows m = 4*b; other rows stay zero forever.
//
// R7: x pipeline deepened by one step. At iter t we read x(t+1) fragments
// (written at iter t-1) and issue layer0's x-side MFMAs for step t+1 at the
// END of the iteration, just before the barrier. That ~350cy of queued
// matrix-pipe work drains across the barrier and hides the next iteration's
// ds_read latency. In-iter MFMA count drops 72 -> 54. Numerics unchanged.
__global__ __launch_bounds__(256, 1) void gru_mfma(
    const float* __restrict__ x,
    const float* __restrict__ Wih0, const float* __restrict__ Whh0,
    const float* __restrict__ bih0, const float* __restrict__ bhh0,
    const float* __restrict__ Wih1, const float* __restrict__ Whh1,
    const float* __restrict__ bih1, const float* __restrict__ bhh1,
    const float* __restrict__ W1, const float* __restrict__ b1,
    const float* __restrict__ W2, const float* __restrict__ b2,
    float* __restrict__ out)
{
  const int tid  = threadIdx.x;
  const int lane = tid & 63;
  const int wv   = tid >> 6;
  const int nloc = lane & 15;
  const int quad = lane >> 4;
  const int b0   = blockIdx.x << 2;

  __shared__ __align__(16) short xsH[2][1024], xsL[2][1024];
  __shared__ __align__(16) short hAH[2][1024], hAL[2][1024];
  __shared__ __align__(16) short hBH[2][1024], hBL[2][1024];
  __shared__ float hfin[256];
  __shared__ float msf[128];

  // ---- weight B-fragments (verified layout, unchanged) ----
  const int wrowoff = (16 * wv + nloc) * HID + 8 * quad;
  WFRAG(i0r, Wih0, 0); WFRAG(i0z, Wih0, 1); WFRAG(i0n, Wih0, 2);
  WFRAG(h0r, Whh0, 0); WFRAG(h0z, Whh0, 1); WFRAG(h0n, Whh0, 2);
  WFRAG(i1r, Wih1, 0); WFRAG(i1z, Wih1, 1); WFRAG(i1n, Wih1, 2);
  WFRAG(h1r, Whh1, 0); WFRAG(h1z, Whh1, 1); WFRAG(h1n, Whh1, 2);

  const int jg = 16 * wv + nloc;
  const float bA_r = bih0[jg] + bhh0[jg];
  const float bA_z = bih0[jg + 64] + bhh0[jg + 64];
  const float bA_i = bih0[jg + 128], bA_h = bhh0[jg + 128];
  const float bB_r = bih1[jg] + bhh1[jg];
  const float bB_z = bih1[jg + 64] + bhh1[jg + 64];
  const float bB_i = bih1[jg + 128], bB_h = bhh1[jg + 128];

  // loop-invariant LDS indices (shorts)
  const int ra0 = nloc * 64 + (((quad    ) ^ (nloc & 7)) << 3);
  const int ra1 = nloc * 64 + (((quad + 4) ^ (nloc & 7)) << 3);
  const int hwr = quad * 256 + (((jg >> 3) ^ ((quad & 1) << 2)) << 3) + (jg & 7);
  const int xwr = wv * 256 + (((lane >> 3) ^ ((wv & 1) << 2)) << 3) + (lane & 7);

  const float* xptr = x + ((size_t)(b0 + wv) * HID + lane) * T_STEPS;

  for (int i = tid; i < 1024; i += 256) {
    xsH[0][i] = 0; xsL[0][i] = 0; hAH[0][i] = 0; hAL[0][i] = 0; hBH[0][i] = 0; hBL[0][i] = 0;
    xsH[1][i] = 0; xsL[1][i] = 0; hAH[1][i] = 0; hAL[1][i] = 0; hBH[1][i] = 0; hBL[1][i] = 0;
  }
  __syncthreads();
  // seed x(0) in buffer 0 (prologue hoist reads it), x(1) in buffer 1 (iter 0 reads it)
  { short h, l;
    split1(xptr[0], &h, &l); xsH[0][xwr] = h; xsL[0][xwr] = l;
    split1(xptr[1], &h, &l); xsH[1][xwr] = h; xsL[1][xwr] = l; }
  __syncthreads();

  const f32x4 z4 = {0.f, 0.f, 0.f, 0.f};

  // persistent layer0 x-side partials for step t (computed one iter ahead)
  f32x4 pRx0, pRx1, pZx0, pZx1, pI0, pI1;
  {
    bf16x8 NH0 = *(const bf16x8*)&xsH[0][ra0], NH1 = *(const bf16x8*)&xsH[0][ra1];
    bf16x8 NL0 = *(const bf16x8*)&xsL[0][ra0], NL1 = *(const bf16x8*)&xsL[0][ra1];
    pRx0 = z4; pRx1 = z4; pZx0 = z4; pZx1 = z4; pI0 = z4; pI1 = z4;
    G3C0(pRx0, NH0, NL0, i0r); G3C1(pRx1, NH1, NL1, i0r);
    G3C0(pZx0, NH0, NL0, i0z); G3C1(pZx1, NH1, NL1, i0z);
    G3C0(pI0,  NH0, NL0, i0n); G3C1(pI1,  NH1, NL1, i0n);
  }

  float hpa = 0.f, hpb = 0.f;   // lane's h[batch=quad][j=jg]; hpb lags one step

  #pragma unroll 1
  for (int t = 0; t < T_STEPS; ++t) {
    const int rb = (t & 1) ^ 1;   // read buffer (written during iter t-1)
    const int wb = t & 1;         // write buffer
    float xnn = (t < T_STEPS - 2) ? xptr[t + 2] : 0.f;

    // ---- reads: A = hA(t-1), B = hB(t-2), N = x(t+1) ----
    bf16x8 AH0 = *(const bf16x8*)&hAH[rb][ra0], AH1 = *(const bf16x8*)&hAH[rb][ra1];
    bf16x8 AL0 = *(const bf16x8*)&hAL[rb][ra0], AL1 = *(const bf16x8*)&hAL[rb][ra1];
    bf16x8 BH0 = *(const bf16x8*)&hBH[rb][ra0], BH1 = *(const bf16x8*)&hBH[rb][ra1];
    bf16x8 BL0 = *(const bf16x8*)&hBL[rb][ra0], BL1 = *(const bf16x8*)&hBL[rb][ra1];
    bf16x8 NH0 = *(const bf16x8*)&xsH[rb][ra0], NH1 = *(const bf16x8*)&xsH[rb][ra1];
    bf16x8 NL0 = *(const bf16x8*)&xsL[rb][ra0], NL1 = *(const bf16x8*)&xsL[rb][ra1];

    // ---- layer 0 h-side, step t (R,Z first so gate math can start early) ----
    f32x4 aRh0 = z4, aRh1 = z4, aZh0 = z4, aZh1 = z4, aHh0 = z4, aHh1 = z4;
    G3C0(aRh0, AH0, AL0, h0r); G3C1(aRh1, AH1, AL1, h0r);
    G3C0(aZh0, AH0, AL0, h0z); G3C1(aZh1, AH1, AL1, h0z);
    G3C0(aHh0, AH0, AL0, h0n); G3C1(aHh1, AH1, AL1, h0n);

    // ---- layer 1, step t-1 ----
    f32x4 cRh0 = z4, cRh1 = z4, cRx0 = z4, cRx1 = z4;
    f32x4 cZh0 = z4, cZh1 = z4, cZx0 = z4, cZx1 = z4;
    f32x4 cHh0 = z4, cHh1 = z4, cI0  = z4, cI1  = z4;
    G3C0(cRh0, BH0, BL0, h1r); G3C1(cRh1, BH1, BL1, h1r);
    G3C0(cRx0, AH0, AL0, i1r); G3C1(cRx1, AH1, AL1, i1r);
    G3C0(cZh0, BH0, BL0, h1z); G3C1(cZh1, BH1, BL1, h1z);
    G3C0(cZx0, AH0, AL0, i1z); G3C1(cZx1, AH1, AL1, i1z);
    G3C0(cHh0, BH0, BL0, h1n); G3C1(cHh1, BH1, BL1, h1n);
    G3C0(cI0,  AH0, AL0, i1n); G3C1(cI1,  AH1, AL1, i1n);

    // ---- layer 0 gate math -> hA(t)  (x-side partials from previous iter) ----
    {
      float r = sigm((pRx0[0] + pRx1[0]) + (aRh0[0] + aRh1[0]) + bA_r);
      float z = sigm((pZx0[0] + pZx1[0]) + (aZh0[0] + aZh1[0]) + bA_z);
      float n = tanh_fast(((pI0[0] + pI1[0]) + bA_i) + r * ((aHh0[0] + aHh1[0]) + bA_h));
      hpa = n + z * (hpa - n);
      short h, l; split1(hpa, &h, &l);
      hAH[wb][hwr] = h; hAL[wb][hwr] = l;
    }
    // ---- layer 1 gate math -> hB(t-1); t==0 writes zeros (== hB(-1)) ----
    {
      float r = sigm((cRx0[0] + cRx1[0]) + (cRh0[0] + cRh1[0]) + bB_r);
      float z = sigm((cZx0[0] + cZx1[0]) + (cZh0[0] + cZh1[0]) + bB_z);
      float n = tanh_fast(((cI0[0] + cI1[0]) + bB_i) + r * ((cHh0[0] + cHh1[0]) + bB_h));
      hpb = (t > 0) ? (n + z * (hpb - n)) : 0.f;
      short h, l; split1(hpb, &h, &l);
      hBH[wb][hwr] = h; hBL[wb][hwr] = l;
    }
    { short h, l; split1(xnn, &h, &l); xsH[wb][xwr] = h; xsL[wb][xwr] = l; }

    // ---- hoist: layer0 x-side for step t+1; queued pipe work drains across
    //      the barrier and covers next iter's ds_read latency ----
    pRx0 = z4; pRx1 = z4; pZx0 = z4; pZx1 = z4; pI0 = z4; pI1 = z4;
    G3C0(pRx0, NH0, NL0, i0r); G3C1(pRx1, NH1, NL1, i0r);
    G3C0(pZx0, NH0, NL0, i0z); G3C1(pZx1, NH1, NL1, i0z);
    G3C0(pI0,  NH0, NL0, i0n); G3C1(pI1,  NH1, NL1, i0n);

    __syncthreads();                       // single barrier per step
  }

  // ---- epilogue: layer 1, step T-1 (reads buffers written at iter T-1) ----
  {
    const int rb = (T_STEPS - 1) & 1;      // == 1
    bf16x8 AH0 = *(const bf16x8*)&hAH[rb][ra0], AH1 = *(const bf16x8*)&hAH[rb][ra1];
    bf16x8 AL0 = *(const bf16x8*)&hAL[rb][ra0], AL1 = *(const bf16x8*)&hAL[rb][ra1];
    bf16x8 BH0 = *(const bf16x8*)&hBH[rb][ra0], BH1 = *(const bf16x8*)&hBH[rb][ra1];
    bf16x8 BL0 = *(const bf16x8*)&hBL[rb][ra0], BL1 = *(const bf16x8*)&hBL[rb][ra1];

    f32x4 cRh0 = z4, cRh1 = z4, cRx0 = z4, cRx1 = z4;
    f32x4 cZh0 = z4, cZh1 = z4, cZx0 = z4, cZx1 = z4;
    f32x4 cHh0 = z4, cHh1 = z4, cI0  = z4, cI1  = z4;
    G3C0(cRh0, BH0, BL0, h1r); G3C1(cRh1, BH1, BL1, h1r);
    G3C0(cHh0, BH0, BL0, h1n); G3C1(cHh1, BH1, BL1, h1n);
    G3C0(cRx0, AH0, AL0, i1r); G3C1(cRx1, AH1, AL1, i1r);
    G3C0(cI0,  AH0, AL0, i1n); G3C1(cI1,  AH1, AL1, i1n);
    G3C0(cZh0, BH0, BL0, h1z); G3C1(cZh1, BH1, BL1, h1z);
    G3C0(cZx0, AH0, AL0, i1z); G3C1(cZx1, AH1, AL1, i1z);

    float r = sigm((cRx0[0] + cRx1[0]) + (cRh0[0] + cRh1[0]) + bB_r);
    float z = sigm((cZx0[0] + cZx1[0]) + (cZh0[0] + cZh1[0]) + bB_z);
    float n = tanh_fast(((cI0[0] + cI1[0]) + bB_i) + r * ((cHh0[0] + cHh1[0]) + bB_h));
    hpb = n + z * (hpb - n);
    hfin[quad * 64 + jg] = hpb;
  }
  __syncthreads();

  // ---- classifier on hfin = hB(T-1), fp32 ----
  if (tid < 128) {
    const int bb = tid >> 5, u = tid & 31;
    float acc = b1[u];
    const float* w1r = W1 + u * HID;
    #pragma unroll
    for (int k = 0; k < 64; ++k)
      acc = fmaf(w1r[k], hfin[bb * 64 + k], acc);
    msf[(bb << 5) + u] = fmaxf(acc, 0.f);
  }
  __syncthreads();
  if (tid < 16) {
    const int bb = tid >> 2, c = tid & 3;
    float acc = b2[c];
    const float* w2r = W2 + (c << 5);
    #pragma unroll
    for (int u = 0; u < 32; ++u)
      acc = fmaf(w2r[u], msf[(bb << 5) + u], acc);
    out[(size_t)(b0 + bb) * 4 + c] = acc;
  }
}

extern "C" void kernel_launch(void* const* d_in, const int* in_sizes, int n_in,
                              void* d_out, int out_size, void* d_ws, size_t ws_size,
                              hipStream_t stream) {
  const float* x    = (const float*)d_in[0];
  const float* Wih0 = (const float*)d_in[1];
  const float* Whh0 = (const float*)d_in[2];
  const float* bih0 = (const float*)d_in[3];
  const float* bhh0 = (const float*)d_in[4];
  const float* Wih1 = (const float*)d_in[5];
  const float* Whh1 = (const float*)d_in[6];
  const float* bih1 = (const float*)d_in[7];
  const float* bhh1 = (const float*)d_in[8];
  const float* W1   = (const float*)d_in[9];
  const float* b1   = (const float*)d_in[10];
  const float* W2   = (const float*)d_in[11];
  const float* b2   = (const float*)d_in[12];
  float* out = (float*)d_out;

  hipLaunchKernelGGL(gru_mfma, dim3(256), dim3(256), 0, stream,
                     x, Wih0, Whh0, bih0, bhh0, Wih1, Whh1, bih1, bhh1,
                     W1, b1, W2, b2, out);
}

// Round 4
// 525.388 us; speedup vs baseline: 1.1740x; 1.1740x over previous
//
#include <hip/hip_runtime.h>

#define T_STEPS 512
#define HID 64

typedef short bf16x8 __attribute__((ext_vector_type(8)));
typedef float f32x4 __attribute__((ext_vector_type(4)));

__device__ __forceinline__ float sigm(float x) {
  return __builtin_amdgcn_rcpf(1.f + __expf(-x));
}
__device__ __forceinline__ float tanh_fast(float x) {
  return 1.f - 2.f * __builtin_amdgcn_rcpf(__expf(2.f * x) + 1.f);
}

// split fp32 -> bf16 hi (chop) + bf16 lo (chop of exact residual)
__device__ __forceinline__ void split1(float v, short* hi, short* lo) {
  unsigned u = __float_as_uint(v);
  float r = v - __uint_as_float(u & 0xffff0000u);   // exact in fp32
  *hi = (short)(u >> 16);
  *lo = (short)(__float_as_uint(r) >> 16);
}

__device__ __forceinline__ void split8(const float* __restrict__ p, bf16x8& hi, bf16x8& lo) {
  float v[8];
  *(float4*)&v[0] = *(const float4*)p;
  *(float4*)&v[4] = *(const float4*)(p + 4);
  #pragma unroll
  for (int i = 0; i < 8; ++i) {
    unsigned u = __float_as_uint(v[i]);
    float r = v[i] - __uint_as_float(u & 0xffff0000u);
    hi[i] = (short)(u >> 16);
    lo[i] = (short)(__float_as_uint(r) >> 16);
  }
}

#define MM(acc, A, B) acc = __builtin_amdgcn_mfma_f32_16x16x32_bf16((A), (B), (acc), 0, 0, 0)

// R8: value-lo lives in M-row 4b+1 of the SAME A-array (rows 4b = hi).
// One depth-4 chain vs {Wh0,Wh1,Wl0,Wl1} yields acc[0]=vh·(Wh+Wl),
// acc[1]=vl·(Wh+Wl); acc[0]+acc[1] = (vh+vl)·(Wh+Wl) — all 4 terms exact.
// 4 MFMAs per product (was 6), 1 acc per product (was 2-3).
#define GP4(acc, V0, V1, NM) do { \
    MM(acc, V0, NM##h0); MM(acc, V1, NM##h1); \
    MM(acc, V0, NM##l0); MM(acc, V1, NM##l1); } while (0)

#define WFRAG(NM, Wp, goff) \
  bf16x8 NM##h0, NM##l0, NM##h1, NM##l1; \
  split8((Wp) + (goff) * (64 * HID) + wrowoff, NM##h0, NM##l0); \
  split8((Wp) + (goff) * (64 * HID) + wrowoff + 32, NM##h1, NM##l1)

// LDS A-matrices: logical [m(16)][k(64)] bf16, XOR-swizzled in 16B units:
// element idx (shorts) = m*64 + (((k>>3) ^ (m&7))<<3) + (k&7).
// Fragment read (chunk c, lane (nloc,quad)): base = nloc*64 + (((c*4+quad)^(nloc&7))<<3)
// -> conflict-free b128. Batch b: hi at row 4b, lo at row 4b+1; rows 4b+2,3 stay zero.
__global__ __launch_bounds__(256, 1) void gru_mfma(
    const float* __restrict__ x,
    const float* __restrict__ Wih0, const float* __restrict__ Whh0,
    const float* __restrict__ bih0, const float* __restrict__ bhh0,
    const float* __restrict__ Wih1, const float* __restrict__ Whh1,
    const float* __restrict__ bih1, const float* __restrict__ bhh1,
    const float* __restrict__ W1, const float* __restrict__ b1,
    const float* __restrict__ W2, const float* __restrict__ b2,
    float* __restrict__ out)
{
  const int tid  = threadIdx.x;
  const int lane = tid & 63;
  const int wv   = tid >> 6;
  const int nloc = lane & 15;
  const int quad = lane >> 4;
  const int b0   = blockIdx.x << 2;

  __shared__ __align__(16) short xs[2][1024];
  __shared__ __align__(16) short hA[2][1024];
  __shared__ __align__(16) short hB[2][1024];
  __shared__ float hfin[256];
  __shared__ float msf[128];

  // ---- weight B-fragments (verified layout, unchanged) ----
  const int wrowoff = (16 * wv + nloc) * HID + 8 * quad;
  WFRAG(i0r, Wih0, 0); WFRAG(i0z, Wih0, 1); WFRAG(i0n, Wih0, 2);
  WFRAG(h0r, Whh0, 0); WFRAG(h0z, Whh0, 1); WFRAG(h0n, Whh0, 2);
  WFRAG(i1r, Wih1, 0); WFRAG(i1z, Wih1, 1); WFRAG(i1n, Wih1, 2);
  WFRAG(h1r, Whh1, 0); WFRAG(h1z, Whh1, 1); WFRAG(h1n, Whh1, 2);

  const int jg = 16 * wv + nloc;
  const float bA_r = bih0[jg] + bhh0[jg];
  const float bA_z = bih0[jg + 64] + bhh0[jg + 64];
  const float bA_i = bih0[jg + 128], bA_h = bhh0[jg + 128];
  const float bB_r = bih1[jg] + bhh1[jg];
  const float bB_z = bih1[jg + 64] + bhh1[jg + 64];
  const float bB_i = bih1[jg + 128], bB_h = bhh1[jg + 128];

  // loop-invariant LDS indices (shorts)
  const int ra0 = nloc * 64 + (((quad    ) ^ (nloc & 7)) << 3);
  const int ra1 = nloc * 64 + (((quad + 4) ^ (nloc & 7)) << 3);
  // h writes: hi at row 4q (mask (4q)&7 = (q&1)<<2), lo at row 4q+1 (mask |1)
  const int hwrH = quad * 256 +      (((jg >> 3) ^ ( (quad & 1) << 2)     ) << 3) + (jg & 7);
  const int hwrL = quad * 256 + 64 + (((jg >> 3) ^ (((quad & 1) << 2) | 1)) << 3) + (jg & 7);
  // x writes: batch wv at rows 4wv / 4wv+1, col = lane
  const int xwrH = wv * 256 +      (((lane >> 3) ^ ( (wv & 1) << 2)     ) << 3) + (lane & 7);
  const int xwrL = wv * 256 + 64 + (((lane >> 3) ^ (((wv & 1) << 2) | 1)) << 3) + (lane & 7);

  const float* xptr = x + ((size_t)(b0 + wv) * HID + lane) * T_STEPS;
  float xfirst = xptr[0];

  for (int i = tid; i < 2048; i += 256) {
    ((short*)xs)[i] = 0; ((short*)hA)[i] = 0; ((short*)hB)[i] = 0;
  }
  __syncthreads();
  // iter 0 reads buffer 1: seed x(0) there (hA(-1)=hB(-2)=0 already)
  { short h, l; split1(xfirst, &h, &l); xs[1][xwrH] = h; xs[1][xwrL] = l; }
  __syncthreads();

  const f32x4 z4 = {0.f, 0.f, 0.f, 0.f};
  float hpa = 0.f, hpb = 0.f;   // lane's h[batch=quad][j=jg]; hpb lags one step

  #pragma unroll 1
  for (int t = 0; t < T_STEPS; ++t) {
    const int rb = (t & 1) ^ 1;   // read buffer (written during iter t-1)
    const int wb = t & 1;         // write buffer
    float xnext = (t < T_STEPS - 1) ? xptr[t + 1] : 0.f;

    // ---- 6 b128 reads: A = hA(t-1), B = hB(t-2), X = x(t) (hi+lo packed) ----
    bf16x8 A0 = *(const bf16x8*)&hA[rb][ra0], A1 = *(const bf16x8*)&hA[rb][ra1];
    bf16x8 B0 = *(const bf16x8*)&hB[rb][ra0], B1 = *(const bf16x8*)&hB[rb][ra1];
    bf16x8 X0 = *(const bf16x8*)&xs[rb][ra0], X1 = *(const bf16x8*)&xs[rb][ra1];

    // ---- 12 independent depth-4 chains (48 MFMA total) ----
    f32x4 aRh = z4, aZh = z4, aHh = z4, aRx = z4, aZx = z4, aIx = z4;
    f32x4 cRh = z4, cZh = z4, cHh = z4, cRx = z4, cZx = z4, cIx = z4;
    GP4(aRh, A0, A1, h0r);
    GP4(aZh, A0, A1, h0z);
    GP4(aHh, A0, A1, h0n);
    GP4(aRx, X0, X1, i0r);
    GP4(aZx, X0, X1, i0z);
    GP4(aIx, X0, X1, i0n);
    GP4(cRh, B0, B1, h1r);
    GP4(cZh, B0, B1, h1z);
    GP4(cHh, B0, B1, h1n);
    GP4(cRx, A0, A1, i1r);
    GP4(cZx, A0, A1, i1z);
    GP4(cIx, A0, A1, i1n);

    // ---- layer 0 gate math -> hA(t); acc[0]+acc[1] = full-precision product ----
    {
      float r = sigm((aRx[0] + aRx[1]) + (aRh[0] + aRh[1]) + bA_r);
      float z = sigm((aZx[0] + aZx[1]) + (aZh[0] + aZh[1]) + bA_z);
      float n = tanh_fast(((aIx[0] + aIx[1]) + bA_i) + r * ((aHh[0] + aHh[1]) + bA_h));
      hpa = n + z * (hpa - n);
      short h, l; split1(hpa, &h, &l);
      hA[wb][hwrH] = h; hA[wb][hwrL] = l;
    }
    // ---- layer 1 gate math -> hB(t-1); t==0 writes zeros (== hB(-1)) ----
    {
      float r = sigm((cRx[0] + cRx[1]) + (cRh[0] + cRh[1]) + bB_r);
      float z = sigm((cZx[0] + cZx[1]) + (cZh[0] + cZh[1]) + bB_z);
      float n = tanh_fast(((cIx[0] + cIx[1]) + bB_i) + r * ((cHh[0] + cHh[1]) + bB_h));
      hpb = (t > 0) ? (n + z * (hpb - n)) : 0.f;
      short h, l; split1(hpb, &h, &l);
      hB[wb][hwrH] = h; hB[wb][hwrL] = l;
    }
    { short h, l; split1(xnext, &h, &l); xs[wb][xwrH] = h; xs[wb][xwrL] = l; }

    __syncthreads();                       // single barrier per step
  }

  // ---- epilogue: layer 1, step T-1 (reads buffers written at iter T-1) ----
  {
    const int rb = (T_STEPS - 1) & 1;      // == 1
    bf16x8 A0 = *(const bf16x8*)&hA[rb][ra0], A1 = *(const bf16x8*)&hA[rb][ra1];
    bf16x8 B0 = *(const bf16x8*)&hB[rb][ra0], B1 = *(const bf16x8*)&hB[rb][ra1];

    f32x4 cRh = z4, cZh = z4, cHh = z4, cRx = z4, cZx = z4, cIx = z4;
    GP4(cRh, B0, B1, h1r);
    GP4(cZh, B0, B1, h1z);
    GP4(cHh, B0, B1, h1n);
    GP4(cRx, A0, A1, i1r);
    GP4(cZx, A0, A1, i1z);
    GP4(cIx, A0, A1, i1n);

    float r = sigm((cRx[0] + cRx[1]) + (cRh[0] + cRh[1]) + bB_r);
    float z = sigm((cZx[0] + cZx[1]) + (cZh[0] + cZh[1]) + bB_z);
    float n = tanh_fast(((cIx[0] + cIx[1]) + bB_i) + r * ((cHh[0] + cHh[1]) + bB_h));
    hpb = n + z * (hpb - n);
    hfin[quad * 64 + jg] = hpb;
  }
  __syncthreads();

  // ---- classifier on hfin = hB(T-1), fp32 ----
  if (tid < 128) {
    const int bb = tid >> 5, u = tid & 31;
    float acc = b1[u];
    const float* w1r = W1 + u * HID;
    #pragma unroll
    for (int k = 0; k < 64; ++k)
      acc = fmaf(w1r[k], hfin[bb * 64 + k], acc);
    msf[(bb << 5) + u] = fmaxf(acc, 0.f);
  }
  __syncthreads();
  if (tid < 16) {
    const int bb = tid >> 2, c = tid & 3;
    float acc = b2[c];
    const float* w2r = W2 + (c << 5);
    #pragma unroll
    for (int u = 0; u < 32; ++u)
      acc = fmaf(w2r[u], msf[(bb << 5) + u], acc);
    out[(size_t)(b0 + bb) * 4 + c] = acc;
  }
}

extern "C" void kernel_launch(void* const* d_in, const int* in_sizes, int n_in,
                              void* d_out, int out_size, void* d_ws, size_t ws_size,
                              hipStream_t stream) {
  const float* x    = (const float*)d_in[0];
  const float* Wih0 = (const float*)d_in[1];
  const float* Whh0 = (const float*)d_in[2];
  const float* bih0 = (const float*)d_in[3];
  const float* bhh0 = (const float*)d_in[4];
  const float* Wih1 = (const float*)d_in[5];
  const float* Whh1 = (const float*)d_in[6];
  const float* bih1 = (const float*)d_in[7];
  const float* bhh1 = (const float*)d_in[8];
  const float* W1   = (const float*)d_in[9];
  const float* b1   = (const float*)d_in[10];
  const float* W2   = (const float*)d_in[11];
  const float* b2   = (const float*)d_in[12];
  float* out = (float*)d_out;

  hipLaunchKernelGGL(gru_mfma, dim3(256), dim3(256), 0, stream,
                     x, Wih0, Whh0, bih0, bhh0, Wih1, Whh1, bih1, bhh1,
                     W1, b1, W2, b2, out);
}

// Round 6
// 470.938 us; speedup vs baseline: 1.3098x; 1.1156x over previous
//
#include <hip/hip_runtime.h>

#define T_STEPS 512
#define HID 64

typedef short bf16x8 __attribute__((ext_vector_type(8)));
typedef float f32x4 __attribute__((ext_vector_type(4)));

__device__ __forceinline__ float sigm(float x) {
  return __builtin_amdgcn_rcpf(1.f + __expf(-x));
}
__device__ __forceinline__ float tanh_fast(float x) {
  return 1.f - 2.f * __builtin_amdgcn_rcpf(__expf(2.f * x) + 1.f);
}

// split fp32 -> bf16 hi (chop) + bf16 lo (chop of exact residual)
__device__ __forceinline__ void split1(float v, short* hi, short* lo) {
  unsigned u = __float_as_uint(v);
  float r = v - __uint_as_float(u & 0xffff0000u);   // exact in fp32
  *hi = (short)(u >> 16);
  *lo = (short)(__float_as_uint(r) >> 16);
}

__device__ __forceinline__ void split8(const float* __restrict__ p, bf16x8& hi, bf16x8& lo) {
  float v[8];
  *(float4*)&v[0] = *(const float4*)p;
  *(float4*)&v[4] = *(const float4*)(p + 4);
  #pragma unroll
  for (int i = 0; i < 8; ++i) {
    unsigned u = __float_as_uint(v[i]);
    float r = v[i] - __uint_as_float(u & 0xffff0000u);
    hi[i] = (short)(u >> 16);
    lo[i] = (short)(__float_as_uint(r) >> 16);
  }
}

#define MM(acc, A, B) acc = __builtin_amdgcn_mfma_f32_16x16x32_bf16((A), (B), (acc), 0, 0, 0)

// value-lo lives in M-row 4b+1 of the SAME A-array (rows 4b = hi).
// One depth-4 chain vs {Wh0,Wh1,Wl0,Wl1}: acc[0]+acc[1] = (vh+vl)·(Wh+Wl), all terms exact.
#define GP4(acc, V0, V1, NM) do { \
    MM(acc, V0, NM##h0); MM(acc, V1, NM##h1); \
    MM(acc, V0, NM##l0); MM(acc, V1, NM##l1); } while (0)

#define WFRAG(NM, Wp, goff) \
  bf16x8 NM##h0, NM##l0, NM##h1, NM##l1; \
  split8((Wp) + (goff) * (64 * HID) + wrowoff, NM##h0, NM##l0); \
  split8((Wp) + (goff) * (64 * HID) + wrowoff + 32, NM##h1, NM##l1)

// LDS A-matrices: logical [m(16)][k(64)] bf16, XOR-swizzled in 16B units:
// element idx (shorts) = m*64 + (((k>>3) ^ (m&7))<<3) + (k&7).
// Fragment read (chunk c, lane (nloc,quad)): base = nloc*64 + (((c*4+quad)^(nloc&7))<<3)
// -> conflict-free b128. Batch b: hi at row 4b, lo at row 4b+1; rows 4b+2,3 stay zero.
//
// R9: wave specialization by layer. 8 waves (512 thr): waves 0-3 = layer 0,
// waves 4-7 = layer 1, same j-chunks. 2 waves/SIMD -> while one wave is in its
// gate-math/split/ds_write/ds_read serial tail, the other keeps the MFMA pipe
// fed. Per-SIMD MFMA load unchanged (2x24); per-wave weights halve (96 VGPR).
// Role differences are pointer selections; loop body is shared.
__global__ __launch_bounds__(512, 2) void gru_mfma(
    const float* __restrict__ x,
    const float* __restrict__ Wih0, const float* __restrict__ Whh0,
    const float* __restrict__ bih0, const float* __restrict__ bhh0,
    const float* __restrict__ Wih1, const float* __restrict__ Whh1,
    const float* __restrict__ bih1, const float* __restrict__ bhh1,
    const float* __restrict__ W1, const float* __restrict__ b1,
    const float* __restrict__ W2, const float* __restrict__ b2,
    float* __restrict__ out)
{
  const int tid   = threadIdx.x;
  const int lane  = tid & 63;
  const int wv    = tid >> 6;      // 0..7
  const int wq    = wv & 3;        // j-chunk
  const int layer = wv >> 2;       // 0: GRU layer 0, 1: GRU layer 1
  const int nloc  = lane & 15;
  const int quad  = lane >> 4;
  const int b0    = blockIdx.x << 2;

  __shared__ __align__(16) short xs[2][1024];
  __shared__ __align__(16) short hA[2][1024];
  __shared__ __align__(16) short hB[2][1024];
  __shared__ float hfin[256];
  __shared__ float msf[128];

  // ---- per-layer weight/bias selection (wave-uniform) ----
  const float* Wih  = layer ? Wih1 : Wih0;
  const float* Whh  = layer ? Whh1 : Whh0;
  const float* bihp = layer ? bih1 : bih0;
  const float* bhhp = layer ? bhh1 : bhh0;

  const int wrowoff = (16 * wq + nloc) * HID + 8 * quad;
  WFRAG(ir, Wih, 0); WFRAG(iz, Wih, 1); WFRAG(in, Wih, 2);
  WFRAG(hr, Whh, 0); WFRAG(hz, Whh, 1); WFRAG(hn, Whh, 2);

  const int jg = 16 * wq + nloc;
  const float b_r = bihp[jg] + bhhp[jg];
  const float b_z = bihp[jg + 64] + bhhp[jg + 64];
  const float b_i = bihp[jg + 128], b_h = bhhp[jg + 128];

  // loop-invariant LDS indices (shorts)
  const int ra0 = nloc * 64 + (((quad    ) ^ (nloc & 7)) << 3);
  const int ra1 = nloc * 64 + (((quad + 4) ^ (nloc & 7)) << 3);
  const int hwrH = quad * 256 +      (((jg >> 3) ^ ( (quad & 1) << 2)     ) << 3) + (jg & 7);
  const int hwrL = quad * 256 + 64 + (((jg >> 3) ^ (((quad & 1) << 2) | 1)) << 3) + (jg & 7);
  const int xwrH = wq * 256 +      (((lane >> 3) ^ ( (wq & 1) << 2)     ) << 3) + (lane & 7);
  const int xwrL = wq * 256 + 64 + (((lane >> 3) ^ (((wq & 1) << 2) | 1)) << 3) + (lane & 7);

  // own-h array (written by this wave's role) and input array (read-only here):
  // L0: own = hA, in = xs;   L1: own = hB, in = hA.
  short* Hown = layer ? &hB[0][0] : &hA[0][0];
  short* Vin  = layer ? &hA[0][0] : &xs[0][0];

  const float* xptr = x + ((size_t)(b0 + wq) * HID + lane) * T_STEPS;

  for (int i = tid; i < 2048; i += 512) {
    ((short*)xs)[i] = 0; ((short*)hA)[i] = 0; ((short*)hB)[i] = 0;
  }
  __syncthreads();
  // iter 0 reads buffer 1: L0 seeds x(0) there (hA, hB stay zero = h(-1))
  if (!layer) { short h, l; split1(xptr[0], &h, &l); xs[1][xwrH] = h; xs[1][xwrL] = l; }
  __syncthreads();

  const f32x4 z4 = {0.f, 0.f, 0.f, 0.f};
  float hp = 0.f;   // L0: hA[quad][jg]; L1: hB[quad][jg], lagging one step

  #pragma unroll 1
  for (int t = 0; t < T_STEPS; ++t) {
    const int rb = ((t & 1) ^ 1) << 10;  // read offset (shorts)
    const int wb = (t & 1) << 10;        // write offset
    float xnext = 0.f;
    if (!layer) xnext = (t < T_STEPS - 1) ? xptr[t + 1] : 0.f;

    // L0 at iter t computes layer0 step t:   H = hA(t-1), V = x(t)
    // L1 at iter t computes layer1 step t-1: H = hB(t-2), V = hA(t-1)
    bf16x8 H0 = *(const bf16x8*)&Hown[rb + ra0], H1 = *(const bf16x8*)&Hown[rb + ra1];
    bf16x8 V0 = *(const bf16x8*)&Vin[rb + ra0],  V1 = *(const bf16x8*)&Vin[rb + ra1];

    // 6 independent depth-4 chains (24 MFMA)
    f32x4 sRh = z4, sZh = z4, sHh = z4, sRx = z4, sZx = z4, sIx = z4;
    GP4(sRh, H0, H1, hr);
    GP4(sRx, V0, V1, ir);
    GP4(sZh, H0, H1, hz);
    GP4(sZx, V0, V1, iz);
    GP4(sHh, H0, H1, hn);
    GP4(sIx, V0, V1, in);

    {
      float r  = sigm((sRx[0] + sRx[1]) + (sRh[0] + sRh[1]) + b_r);
      float zz = sigm((sZx[0] + sZx[1]) + (sZh[0] + sZh[1]) + b_z);
      float n  = tanh_fast(((sIx[0] + sIx[1]) + b_i) + r * ((sHh[0] + sHh[1]) + b_h));
      float hnew = n + zz * (hp - n);
      hp = (layer && t == 0) ? 0.f : hnew;   // L1 iter0 emits hB(-1) = 0
      short h, l; split1(hp, &h, &l);
      Hown[wb + hwrH] = h; Hown[wb + hwrL] = l;
    }
    if (!layer) { short h, l; split1(xnext, &h, &l);
                  ((short*)xs)[wb + xwrH] = h; ((short*)xs)[wb + xwrL] = l; }

    __syncthreads();                       // single barrier per step
  }

  // ---- epilogue: L1 waves compute layer1 step T-1 ----
  // after iter T-1 (wb=1): hA[1] = hA(T-1), hB[1] = hB(T-2)
  if (layer) {
    const int rb = 1 << 10;
    bf16x8 H0 = *(const bf16x8*)&Hown[rb + ra0], H1 = *(const bf16x8*)&Hown[rb + ra1];
    bf16x8 V0 = *(const bf16x8*)&Vin[rb + ra0],  V1 = *(const bf16x8*)&Vin[rb + ra1];
    f32x4 sRh = z4, sZh = z4, sHh = z4, sRx = z4, sZx = z4, sIx = z4;
    GP4(sRh, H0, H1, hr);
    GP4(sRx, V0, V1, ir);
    GP4(sZh, H0, H1, hz);
    GP4(sZx, V0, V1, iz);
    GP4(sHh, H0, H1, hn);
    GP4(sIx, V0, V1, in);
    float r  = sigm((sRx[0] + sRx[1]) + (sRh[0] + sRh[1]) + b_r);
    float zz = sigm((sZx[0] + sZx[1]) + (sZh[0] + sZh[1]) + b_z);
    float n  = tanh_fast(((sIx[0] + sIx[1]) + b_i) + r * ((sHh[0] + sHh[1]) + b_h));
    hp = n + zz * (hp - n);
    hfin[quad * 64 + jg] = hp;
  }
  __syncthreads();

  // ---- classifier on hfin = hB(T-1), fp32 ----
  if (tid < 128) {
    const int bb = tid >> 5, u = tid & 31;
    float acc = b1[u];
    const float* w1r = W1 + u * HID;
    #pragma unroll
    for (int k = 0; k < 64; ++k)
      acc = fmaf(w1r[k], hfin[bb * 64 + k], acc);
    msf[(bb << 5) + u] = fmaxf(acc, 0.f);
  }
  __syncthreads();
  if (tid < 16) {
    const int bb = tid >> 2, c = tid & 3;
    float acc = b2[c];
    const float* w2r = W2 + (c << 5);
    #pragma unroll
    for (int u = 0; u < 32; ++u)
      acc = fmaf(w2r[u], msf[(bb << 5) + u], acc);
    out[(size_t)(b0 + bb) * 4 + c] = acc;
  }
}

extern "C" void kernel_launch(void* const* d_in, const int* in_sizes, int n_in,
                              void* d_out, int out_size, void* d_ws, size_t ws_size,
                              hipStream_t stream) {
  const float* x    = (const float*)d_in[0];
  const float* Wih0 = (const float*)d_in[1];
  const float* Whh0 = (const float*)d_in[2];
  const float* bih0 = (const float*)d_in[3];
  const float* bhh0 = (const float*)d_in[4];
  const float* Wih1 = (const float*)d_in[5];
  const float* Whh1 = (const float*)d_in[6];
  const float* bih1 = (const float*)d_in[7];
  const float* bhh1 = (const float*)d_in[8];
  const float* W1   = (const float*)d_in[9];
  const float* b1   = (const float*)d_in[10];
  const float* W2   = (const float*)d_in[11];
  const float* b2   = (const float*)d_in[12];
  float* out = (float*)d_out;

  hipLaunchKernelGGL(gru_mfma, dim3(256), dim3(512), 0, stream,
                     x, Wih0, Whh0, bih0, bhh0, Wih1, Whh1, bih1, bhh1,
                     W1, b1, W2, b2, out);
}

// Round 7
// 442.698 us; speedup vs baseline: 1.3933x; 1.0638x over previous
//
#include <hip/hip_runtime.h>

#define T_STEPS 512
#define HID 64

typedef short bf16x8 __attribute__((ext_vector_type(8)));
typedef float f32x4 __attribute__((ext_vector_type(4)));

__device__ __forceinline__ float sigm(float x) {
  return __builtin_amdgcn_rcpf(1.f + __expf(-x));
}
__device__ __forceinline__ float tanh_fast(float x) {
  return 1.f - 2.f * __builtin_amdgcn_rcpf(__expf(2.f * x) + 1.f);
}

// split fp32 -> bf16 hi (chop) + bf16 lo (chop of exact residual)
__device__ __forceinline__ void split1(float v, short* hi, short* lo) {
  unsigned u = __float_as_uint(v);
  float r = v - __uint_as_float(u & 0xffff0000u);   // exact in fp32
  *hi = (short)(u >> 16);
  *lo = (short)(__float_as_uint(r) >> 16);
}

__device__ __forceinline__ void split8(const float* __restrict__ p, bf16x8& hi, bf16x8& lo) {
  float v[8];
  *(float4*)&v[0] = *(const float4*)p;
  *(float4*)&v[4] = *(const float4*)(p + 4);
  #pragma unroll
  for (int i = 0; i < 8; ++i) {
    unsigned u = __float_as_uint(v[i]);
    float r = v[i] - __uint_as_float(u & 0xffff0000u);
    hi[i] = (short)(u >> 16);
    lo[i] = (short)(__float_as_uint(r) >> 16);
  }
}

#define MM(acc, A, B) acc = __builtin_amdgcn_mfma_f32_16x16x32_bf16((A), (B), (acc), 0, 0, 0)

// value-lo lives in M-row 4b+1 of the SAME A-array (rows 4b = hi).
// One depth-4 chain vs {Wh0,Wh1,Wl0,Wl1}: acc[0]+acc[1] = (vh+vl)·(Wh+Wl), all terms exact.
#define GP4(acc, V0, V1, NM) do { \
    MM(acc, V0, NM##h0); MM(acc, V1, NM##h1); \
    MM(acc, V0, NM##l0); MM(acc, V1, NM##l1); } while (0)

#define WFRAG(NM, Wp, goff) \
  bf16x8 NM##h0, NM##l0, NM##h1, NM##l1; \
  split8((Wp) + (goff) * (64 * HID) + wrowoff, NM##h0, NM##l0); \
  split8((Wp) + (goff) * (64 * HID) + wrowoff + 32, NM##h1, NM##l1)

// LDS A-matrices: logical [m(16)][k(64)] bf16, XOR-swizzled in 16B units:
// element idx (shorts) = m*64 + (((k>>3) ^ (m&7))<<3) + (k&7). Conflict-free b128.
// Batch b: hi at row 4b, lo at row 4b+1; rows 4b+2,3 stay zero.
//
// R9: wave specialization by layer (waves 0-3 = L0, 4-7 = L1; 2 waves/SIMD).
// R10: break L0/L1 lockstep + shave serial tail:
//   - s_setprio(1) around the MFMA cluster (T5; role diversity exists now)
//   - r/z chains first, sigmoids computed while n-side MFMAs issue
//   - biases folded into MFMA C-init ({b,0,0,0})
//   - 2x unroll: compile-time ping-pong offsets (immediate ds offsets)
__global__ __launch_bounds__(512, 2) void gru_mfma(
    const float* __restrict__ x,
    const float* __restrict__ Wih0, const float* __restrict__ Whh0,
    const float* __restrict__ bih0, const float* __restrict__ bhh0,
    const float* __restrict__ Wih1, const float* __restrict__ Whh1,
    const float* __restrict__ bih1, const float* __restrict__ bhh1,
    const float* __restrict__ W1, const float* __restrict__ b1,
    const float* __restrict__ W2, const float* __restrict__ b2,
    float* __restrict__ out)
{
  const int tid   = threadIdx.x;
  const int lane  = tid & 63;
  const int wv    = tid >> 6;      // 0..7
  const int wq    = wv & 3;        // j-chunk
  const int layer = wv >> 2;       // 0: GRU layer 0, 1: GRU layer 1
  const int nloc  = lane & 15;
  const int quad  = lane >> 4;
  const int b0    = blockIdx.x << 2;

  __shared__ __align__(16) short xs[2][1024];
  __shared__ __align__(16) short hA[2][1024];
  __shared__ __align__(16) short hB[2][1024];
  __shared__ float hfin[256];
  __shared__ float msf[128];

  // ---- per-layer weight/bias selection (wave-uniform) ----
  const float* Wih  = layer ? Wih1 : Wih0;
  const float* Whh  = layer ? Whh1 : Whh0;
  const float* bihp = layer ? bih1 : bih0;
  const float* bhhp = layer ? bhh1 : bhh0;

  const int wrowoff = (16 * wq + nloc) * HID + 8 * quad;
  WFRAG(ir, Wih, 0); WFRAG(iz, Wih, 1); WFRAG(in, Wih, 2);
  WFRAG(hr, Whh, 0); WFRAG(hz, Whh, 1); WFRAG(hn, Whh, 2);

  const int jg = 16 * wq + nloc;
  const float b_r = bihp[jg] + bhhp[jg];
  const float b_z = bihp[jg + 64] + bhhp[jg + 64];
  const float b_i = bihp[jg + 128], b_h = bhhp[jg + 128];

  // loop-invariant LDS indices (shorts)
  const int ra0 = nloc * 64 + (((quad    ) ^ (nloc & 7)) << 3);
  const int ra1 = nloc * 64 + (((quad + 4) ^ (nloc & 7)) << 3);
  const int hwrH = quad * 256 +      (((jg >> 3) ^ ( (quad & 1) << 2)     ) << 3) + (jg & 7);
  const int hwrL = quad * 256 + 64 + (((jg >> 3) ^ (((quad & 1) << 2) | 1)) << 3) + (jg & 7);
  const int xwrH = wq * 256 +      (((lane >> 3) ^ ( (wq & 1) << 2)     ) << 3) + (lane & 7);
  const int xwrL = wq * 256 + 64 + (((lane >> 3) ^ (((wq & 1) << 2) | 1)) << 3) + (lane & 7);

  // own-h array (written by this wave's role) and input array (read-only here):
  // L0: own = hA, in = xs;   L1: own = hB, in = hA.
  short* Hown = layer ? &hB[0][0] : &hA[0][0];
  short* Vin  = layer ? &hA[0][0] : &xs[0][0];

  const float* xptr = x + ((size_t)(b0 + wq) * HID + lane) * T_STEPS;

  for (int i = tid; i < 2048; i += 512) {
    ((short*)xs)[i] = 0; ((short*)hA)[i] = 0; ((short*)hB)[i] = 0;
  }
  __syncthreads();
  // iter 0 reads buffer 1: L0 seeds x(0) there (hA, hB stay zero = h(-1))
  if (!layer) { short h, l; split1(xptr[0], &h, &l); xs[1][xwrH] = h; xs[1][xwrL] = l; }
  __syncthreads();

  float hp = 0.f;   // L0: hA[quad][jg]; L1: hB[quad][jg], lagging one step

  // One GRU step for this wave's role.  RB/WB = compile-time short offsets.
  // x(TT+1) write wraps at TT=511: value lands in a buffer never read again.
  #define STEP_BODY(RB, WB, F0, TT) do { \
    bf16x8 H0 = *(const bf16x8*)&Hown[(RB) + ra0], H1 = *(const bf16x8*)&Hown[(RB) + ra1]; \
    bf16x8 V0 = *(const bf16x8*)&Vin[(RB) + ra0],  V1 = *(const bf16x8*)&Vin[(RB) + ra1]; \
    float xn = 0.f; \
    if (!layer) xn = xptr[((TT) + 1) & (T_STEPS - 1)]; \
    f32x4 sRh = {b_r, 0.f, 0.f, 0.f}, sRx = {0.f, 0.f, 0.f, 0.f}; \
    f32x4 sZh = {b_z, 0.f, 0.f, 0.f}, sZx = {0.f, 0.f, 0.f, 0.f}; \
    f32x4 sHh = {b_h, 0.f, 0.f, 0.f}, sIx = {b_i, 0.f, 0.f, 0.f}; \
    __builtin_amdgcn_s_setprio(1); \
    GP4(sRh, H0, H1, hr); GP4(sRx, V0, V1, ir); \
    GP4(sZh, H0, H1, hz); GP4(sZx, V0, V1, iz); \
    float rr = sigm((sRx[0] + sRx[1]) + (sRh[0] + sRh[1])); \
    float zz = sigm((sZx[0] + sZx[1]) + (sZh[0] + sZh[1])); \
    GP4(sHh, H0, H1, hn); GP4(sIx, V0, V1, in); \
    __builtin_amdgcn_s_setprio(0); \
    float n = tanh_fast((sIx[0] + sIx[1]) + rr * (sHh[0] + sHh[1])); \
    float hnew = n + zz * (hp - n); \
    hp = ((F0) && layer && (TT) == 0) ? 0.f : hnew; \
    { short h, l; split1(hp, &h, &l); Hown[(WB) + hwrH] = h; Hown[(WB) + hwrL] = l; } \
    if (!layer) { short h, l; split1(xn, &h, &l); \
                  ((short*)xs)[(WB) + xwrH] = h; ((short*)xs)[(WB) + xwrL] = l; } \
    __syncthreads(); \
  } while (0)

  #pragma unroll 1
  for (int t = 0; t < T_STEPS; t += 2) {
    STEP_BODY(1024, 0, 1, t);        // even t: read buf1, write buf0
    STEP_BODY(0, 1024, 0, t + 1);    // odd t:  read buf0, write buf1
  }
  #undef STEP_BODY

  // ---- epilogue: L1 waves compute layer1 step T-1 ----
  // after iter T-1 (WB=1024): hA[1] = hA(T-1), hB[1] = hB(T-2)
  if (layer) {
    const f32x4 z4 = {0.f, 0.f, 0.f, 0.f};
    const int rb = 1 << 10;
    bf16x8 H0 = *(const bf16x8*)&Hown[rb + ra0], H1 = *(const bf16x8*)&Hown[rb + ra1];
    bf16x8 V0 = *(const bf16x8*)&Vin[rb + ra0],  V1 = *(const bf16x8*)&Vin[rb + ra1];
    f32x4 sRh = z4, sZh = z4, sHh = z4, sRx = z4, sZx = z4, sIx = z4;
    GP4(sRh, H0, H1, hr);
    GP4(sRx, V0, V1, ir);
    GP4(sZh, H0, H1, hz);
    GP4(sZx, V0, V1, iz);
    GP4(sHh, H0, H1, hn);
    GP4(sIx, V0, V1, in);
    float r  = sigm((sRx[0] + sRx[1]) + (sRh[0] + sRh[1]) + b_r);
    float zz = sigm((sZx[0] + sZx[1]) + (sZh[0] + sZh[1]) + b_z);
    float n  = tanh_fast(((sIx[0] + sIx[1]) + b_i) + r * ((sHh[0] + sHh[1]) + b_h));
    hp = n + zz * (hp - n);
    hfin[quad * 64 + jg] = hp;
  }
  __syncthreads();

  // ---- classifier on hfin = hB(T-1), fp32 ----
  if (tid < 128) {
    const int bb = tid >> 5, u = tid & 31;
    float acc = b1[u];
    const float* w1r = W1 + u * HID;
    #pragma unroll
    for (int k = 0; k < 64; ++k)
      acc = fmaf(w1r[k], hfin[bb * 64 + k], acc);
    msf[(bb << 5) + u] = fmaxf(acc, 0.f);
  }
  __syncthreads();
  if (tid < 16) {
    const int bb = tid >> 2, c = tid & 3;
    float acc = b2[c];
    const float* w2r = W2 + (c << 5);
    #pragma unroll
    for (int u = 0; u < 32; ++u)
      acc = fmaf(w2r[u], msf[(bb << 5) + u], acc);
    out[(size_t)(b0 + bb) * 4 + c] = acc;
  }
}

extern "C" void kernel_launch(void* const* d_in, const int* in_sizes, int n_in,
                              void* d_out, int out_size, void* d_ws, size_t ws_size,
                              hipStream_t stream) {
  const float* x    = (const float*)d_in[0];
  const float* Wih0 = (const float*)d_in[1];
  const float* Whh0 = (const float*)d_in[2];
  const float* bih0 = (const float*)d_in[3];
  const float* bhh0 = (const float*)d_in[4];
  const float* Wih1 = (const float*)d_in[5];
  const float* Whh1 = (const float*)d_in[6];
  const float* bih1 = (const float*)d_in[7];
  const float* bhh1 = (const float*)d_in[8];
  const float* W1   = (const float*)d_in[9];
  const float* b1   = (const float*)d_in[10];
  const float* W2   = (const float*)d_in[11];
  const float* b2   = (const float*)d_in[12];
  float* out = (float*)d_out;

  hipLaunchKernelGGL(gru_mfma, dim3(256), dim3(512), 0, stream,
                     x, Wih0, Whh0, bih0, bhh0, Wih1, Whh1, bih1, bhh1,
                     W1, b1, W2, b2, out);
}